// Round 10
// baseline (335.038 us; speedup 1.0000x reference)
//
#include <hip/hip_runtime.h>

#define NNODES 50000
#define DIN 128
#define DHID 128
#define DOUT 128
#define NEG_SLOPE 0.01f
#define NT 12500   // 1,600,000 rows / 128
#define GG 256     // persistent grid: 1 block per CU

typedef _Float16 f16x8 __attribute__((ext_vector_type(8)));
typedef _Float16 f16x4 __attribute__((ext_vector_type(4)));
typedef _Float16 f16x2 __attribute__((ext_vector_type(2)));
typedef float f32x4 __attribute__((ext_vector_type(4)));

__device__ __forceinline__ f16x2 pkrtz(float a, float b) {
    return __builtin_bit_cast(f16x2, __builtin_amdgcn_cvt_pkrtz(a, b));
}

// d_ws layout (halves):
//  WqB hi: [ct(8)][g(4)][l(64)][8]   = 16384 halves
//  WqB lo: 16384
//  WwB hi: [ct(8)][g(8)][l(64)][8]   = 32768 halves
//  WwB lo: 32768
#define WS_WQ_HI 0
#define WS_WQ_LO 16384
#define WS_WW_HI 32768
#define WS_WW_LO 65536

__device__ __forceinline__ void gload_lds16(const float* g, float* lds) {
    __builtin_amdgcn_global_load_lds(
        (const __attribute__((address_space(1))) void*)g,
        (__attribute__((address_space(3))) void*)lds, 16, 0, 0);
}

// ---------------------------------------------------------------- kernel 0
// Convert weights to fp16 hi/lo fragment slabs.
// Fragment convention (mfma_f32_16x16x32_f16):
//   A: row = l&15, k = (l>>4)*8 + j
//   B: col = l&15, k = (l>>4)*8 + j
//   D: col = l&15, row = (l>>4)*4 + r
__global__ void convert_weights(const float* __restrict__ Wq,
                                const float* __restrict__ Ww,
                                _Float16* __restrict__ ws) {
    int id = blockIdx.x * 256 + threadIdx.x;
    if (id < 2048) {  // Wq slots: B[k][col] = Wq[col][k]
        int s  = id;
        int l  = s & 63;
        int g  = (s >> 6) & 3;
        int ct = s >> 8;
        int col = ct * 16 + (l & 15);
        int k0  = g * 32 + (l >> 4) * 8;
        const float* src = Wq + col * DIN + k0;
        f16x8 vh, vl;
#pragma unroll
        for (int j = 0; j < 8; ++j) {
            float v = src[j];
            _Float16 h = (_Float16)v;
            vh[j] = h;
            vl[j] = (_Float16)(v - (float)h);
        }
        *(f16x8*)(ws + WS_WQ_HI + s * 8) = vh;
        *(f16x8*)(ws + WS_WQ_LO + s * 8) = vl;
    } else if (id < 2048 + 4096) {  // Ww slots: B2[k][o] = Ww[o][k]
        int s  = id - 2048;
        int l  = s & 63;
        int g  = (s >> 6) & 7;
        int ct = s >> 9;
        int col = ct * 16 + (l & 15);
        int k0  = g * 32 + (l >> 4) * 8;
        const float* src = Ww + col * (DIN + DHID) + k0;
        f16x8 vh, vl;
#pragma unroll
        for (int j = 0; j < 8; ++j) {
            float v = src[j];
            _Float16 h = (_Float16)v;
            vh[j] = h;
            vl[j] = (_Float16)(v - (float)h);
        }
        *(f16x8*)(ws + WS_WW_HI + s * 8) = vh;
        *(f16x8*)(ws + WS_WW_LO + s * 8) = vl;
    }
}

// ---------------------------------------------------------------- kernel 1
// GEMM1 + leaky + alpha-weighted mean -> hagg (= d_out).
// ROW-CHUNKED persistent ring: a chunk = 32 complete rows (ONE node's
// neighbors) = 16KB CONTIGUOUS in hng -> HBM stream is byte-sequential
// (R9's k-chunked 128B@512B-stride slices ran at ~65% DRAM efficiency).
// 8 waves = 2 rgrp x 4 cgrp; wave tile 16 rows x 32 cols x K=128.
// 3-slab ring, stage 2 chunks ahead; per-chunk per-wave queue = S(2) W(1)
// A(1), symmetric across waves -> uniform vmcnt(6) every chunk.
// LDS swizzle: As[row][o] = A[row][o ^ ((row&7)<<4)] via pre-swizzled
// global source (contiguous window permutation) + swizzled ds_read.
// Per-chunk epilogue: alpha-reduce 32 rows -> 1 node; cross-rgrp combine
// through 1KB LDS buffer with lgkmcnt(0)+raw s_barrier (NO __syncthreads
// -- it would drain vmcnt and kill the ring).
__global__ __launch_bounds__(512, 2) void gemm1_agg(
    const float* __restrict__ hng,    // [NNODES*32][128]
    const float* __restrict__ alpha,  // [NNODES*32]
    const float* __restrict__ bq,     // [128]
    const _Float16* __restrict__ ws,
    float* __restrict__ hagg)         // [NNODES][128]
{
    __shared__ float As[3][4096];          // 3-slab ring, 48KB
    __shared__ float px[2][4][2][16];      // [rgrp][cgrp][ct][col16]
    __shared__ float pxa[2];               // alpha-sum per rgrp

    const int tid  = threadIdx.x;
    const int l    = tid & 63;
    const int wid  = tid >> 6;         // 0..7
    const int rgrp = wid >> 2;         // 0..1 (16-row half of the node)
    const int cgrp = wid & 3;          // 0..3 (32-col group)
    const int r16  = l & 15;
    const int kg   = l >> 4;

    const _Float16* wqh = ws + WS_WQ_HI;
    const _Float16* wql = ws + WS_WQ_LO;

    // ---- permanent B fragments: 4 k-frags x 2 col-tiles, hi+lo (64 VGPR)
    f16x8 bh[4][2], bl[4][2];
#pragma unroll
    for (int kf = 0; kf < 4; ++kf)
#pragma unroll
        for (int ct = 0; ct < 2; ++ct) {
            int off = (((cgrp * 2 + ct) * 4 + kf) * 64 + l) * 8;
            bh[kf][ct] = *(const f16x8*)(wqh + off);
            bl[kf][ct] = *(const f16x8*)(wql + off);
        }

    // ---- staging source offsets (floats), per lane, instr i=0,1.
    // instr i covers slab bytes (wid*2+i)*1024 (lane adds l*16 in HW).
    // row rr = wid*4 + 2i + (l>>5); within-row byte o=(l&31)*16;
    // source = row-linear with inverse swizzle o ^ ((rr&7)<<4).
    int so[2];
#pragma unroll
    for (int i = 0; i < 2; ++i) {
        int rr = wid * 4 + i * 2 + (l >> 5);
        int o  = (l & 31) * 16;
        so[i]  = rr * 128 + (((o ^ ((rr & 7) << 4))) >> 2);
    }

    // ---- A-read geometry
    const int arow = rgrp * 16 + r16;      // row within 32-row chunk
    const int asw  = (arow & 7) << 4;      // swizzle for this row

    float bqv[2];
#pragma unroll
    for (int ct = 0; ct < 2; ++ct)
        bqv[ct] = bq[cgrp * 32 + ct * 16 + r16];

#define STAGE(node, s)                                                        \
    do {                                                                      \
        const float* gb_ = hng + (long)(node) * 4096;                         \
        char* lb_ = (char*)&As[s][0];                                         \
        gload_lds16(gb_ + so[0], (float*)(lb_ + (wid * 2 + 0) * 1024));       \
        gload_lds16(gb_ + so[1], (float*)(lb_ + (wid * 2 + 1) * 1024));       \
    } while (0)

#define COMPUTE(s)                                                            \
    do {                                                                      \
        const char* sb_ = (const char*)&As[s][0] + arow * 512;                \
        _Pragma("unroll")                                                     \
        for (int kf_ = 0; kf_ < 4; ++kf_) {                                   \
            int kb_ = kf_ * 128 + kg * 32;                                    \
            f32x4 v0_ = *(const f32x4*)(sb_ + ((kb_ + 0) ^ asw));             \
            f32x4 v1_ = *(const f32x4*)(sb_ + ((kb_ + 16) ^ asw));            \
            f16x2 p0_ = pkrtz(v0_[0], v0_[1]);                                \
            f16x2 p1_ = pkrtz(v0_[2], v0_[3]);                                \
            f16x2 p2_ = pkrtz(v1_[0], v1_[1]);                                \
            f16x2 p3_ = pkrtz(v1_[2], v1_[3]);                                \
            f16x8 ah_;                                                        \
            ah_[0] = p0_[0]; ah_[1] = p0_[1];                                 \
            ah_[2] = p1_[0]; ah_[3] = p1_[1];                                 \
            ah_[4] = p2_[0]; ah_[5] = p2_[1];                                 \
            ah_[6] = p3_[0]; ah_[7] = p3_[1];                                 \
            _Pragma("unroll")                                                 \
            for (int ct_ = 0; ct_ < 2; ++ct_) {                               \
                acc[ct_] = __builtin_amdgcn_mfma_f32_16x16x32_f16(            \
                    ah_, bh[kf_][ct_], acc[ct_], 0, 0, 0);                    \
                acc[ct_] = __builtin_amdgcn_mfma_f32_16x16x32_f16(            \
                    ah_, bl[kf_][ct_], acc[ct_], 0, 0, 0);                    \
            }                                                                 \
        }                                                                     \
    } while (0)

// one chunk = one node. n: node computed; nstage: node staged (2 ahead);
// nnext: node whose alpha we prefetch; scmp/sstg: ring slots.
#define CHUNK(n, nstage, nnext, scmp, sstg)                                   \
    do {                                                                      \
        f32x4 acc[2];                                                         \
        acc[0] = (f32x4){0.f, 0.f, 0.f, 0.f};                                 \
        acc[1] = (f32x4){0.f, 0.f, 0.f, 0.f};                                 \
        asm volatile("s_waitcnt vmcnt(6)" ::: "memory");                      \
        __builtin_amdgcn_s_barrier();                                         \
        __builtin_amdgcn_sched_barrier(0);                                    \
        STAGE(nstage, sstg);                                                  \
        __builtin_amdgcn_sched_barrier(0);                                    \
        COMPUTE(scmp);                                                        \
        /* epilogue: +bq, leaky, alpha-weight, reduce 16 rows (this rgrp) */  \
        {                                                                     \
            float p0_ = 0.f, p1_ = 0.f, ap_ = 0.f;                            \
            _Pragma("unroll")                                                 \
            for (int r_ = 0; r_ < 4; ++r_) {                                  \
                float aw_ = av4[r_];                                          \
                ap_ += aw_;                                                   \
                float v_ = acc[0][r_] + bqv[0];                               \
                v_ = (v_ >= 0.f) ? v_ : NEG_SLOPE * v_;                       \
                p0_ += aw_ * v_;                                              \
                v_ = acc[1][r_] + bqv[1];                                     \
                v_ = (v_ >= 0.f) ? v_ : NEG_SLOPE * v_;                       \
                p1_ += aw_ * v_;                                              \
            }                                                                 \
            p0_ += __shfl_xor(p0_, 16); p0_ += __shfl_xor(p0_, 32);           \
            p1_ += __shfl_xor(p1_, 16); p1_ += __shfl_xor(p1_, 32);           \
            ap_ += __shfl_xor(ap_, 16); ap_ += __shfl_xor(ap_, 32);           \
            if (l < 16) {                                                     \
                px[rgrp][cgrp][0][l] = p0_;                                   \
                px[rgrp][cgrp][1][l] = p1_;                                   \
            }                                                                 \
            if (l == 0 && cgrp == 0) pxa[rgrp] = ap_;                         \
            asm volatile("s_waitcnt lgkmcnt(0)" ::: "memory");                \
            __builtin_amdgcn_s_barrier();                                     \
            __builtin_amdgcn_sched_barrier(0);                                \
            if (l < 16) {                                                     \
                float tot_ = px[0][cgrp][rgrp][l] + px[1][cgrp][rgrp][l];     \
                float den_ = pxa[0] + pxa[1];                                 \
                if (den_ == 0.f) den_ = 1.f;                                  \
                hagg[(long)(n) * DHID + cgrp * 32 + rgrp * 16 + l] =          \
                    tot_ / den_;                                              \
            }                                                                 \
            av4 = *(const f32x4*)(alpha + (long)(nnext) * 32 + rgrp * 16 +    \
                                  kg * 4);                                    \
            __builtin_amdgcn_sched_barrier(0);                                \
        }                                                                     \
    } while (0)

    long t = blockIdx.x;

    // ---- prologue: stage chunks 0,1 of first tile; alpha for node t*4
    STAGE(t * 4 + 0, 0);
    STAGE(t * 4 + 1, 1);
    f32x4 av4 = *(const f32x4*)(alpha + (long)(t * 4) * 32 + rgrp * 16 + kg * 4);
    asm volatile("s_waitcnt vmcnt(0)" ::: "memory");
    __builtin_amdgcn_s_barrier();
    __builtin_amdgcn_sched_barrier(0);

    int sl = 0;  // ring slot of chunk 0 of current tile
    for (;;) {
        const bool last = (t + GG >= NT);
        const long tn   = last ? t : t + GG;
        const long n0   = t * 4;
        const long m0   = tn * 4;
        const int s0 = sl;
        const int s1 = (sl + 1 > 2) ? sl - 2 : sl + 1;
        const int s2 = (sl + 2 > 2) ? sl - 1 : sl + 2;

        CHUNK(n0 + 0, n0 + 2, n0 + 1, s0, s2);
        CHUNK(n0 + 1, n0 + 3, n0 + 2, s1, s0);
        CHUNK(n0 + 2, m0 + 0, n0 + 3, s2, s1);
        CHUNK(n0 + 3, m0 + 1, m0 + 0, s0, s2);

        if (last) break;
        t  = tn;
        sl = s1;  // (sl+4) mod 3
    }
    asm volatile("s_waitcnt vmcnt(0)" ::: "memory");  // drain before endpgm

#undef STAGE
#undef COMPUTE
#undef CHUNK
}

// ---------------------------------------------------------------- kernel 2
// GEMM2: out = normalize(leaky(concat(h_node, hagg) @ Ww^T + bw))
// Tile: 128 nodes x 128 out, K=256 in 8 chunks of 32. hagg lives in `out`.
// A single-f16 via pkrtz; B hi+lo; 2 MFMA terms. (unchanged from R9)
__global__ __launch_bounds__(256, 2) void gemm2_norm(
    const float* __restrict__ hnode,  // [NNODES][128]
    const float* __restrict__ bw,     // [128]
    const _Float16* __restrict__ ws,
    float* __restrict__ out)          // [NNODES][128], holds hagg on entry
{
    __shared__ _Float16 Ahi[8 * 520];
    __shared__ _Float16 Bhi[8 * 512];
    __shared__ _Float16 Blo[8 * 512];
    __shared__ float bw_s[128];
    __shared__ float nbuf[2][128];

    const int tid = threadIdx.x;
    const int l   = tid & 63;
    const int wid = tid >> 6;
    const int wr  = wid >> 1, wc = wid & 1;
    const long NB = (long)blockIdx.x * 128;

    if (tid < 128) bw_s[tid] = bw[tid];

    f32x4 acc[4][4];
#pragma unroll
    for (int i = 0; i < 4; ++i)
#pragma unroll
        for (int j = 0; j < 4; ++j) acc[i][j] = (f32x4){0.f, 0.f, 0.f, 0.f};

    const _Float16* wwh = ws + WS_WW_HI;
    const _Float16* wwl = ws + WS_WW_LO;

    for (int c = 0; c < 8; ++c) {
        __syncthreads();
        // ---- stage A: 128 nodes x 32 k of concat(h_node, hagg), f16 single
#pragma unroll
        for (int p = 0; p < 4; ++p) {
            int rl = p * 32 + (tid >> 3);
            long n = NB + rl;
            if (n > NNODES - 1) n = NNODES - 1;  // tail clamp (stores guarded)
            int kw = (tid & 7) * 4;       // within-chunk k
            int kgl = c * 32 + kw;        // global k in 0..255
            const float* g = (kgl < 128) ? (hnode + n * DIN + kgl)
                                         : (out + n * DHID + (kgl - 128));
            f32x4 v = *(const f32x4*)g;
            f16x2 p0 = pkrtz(v[0], v[1]);
            f16x2 p1 = pkrtz(v[2], v[3]);
            f16x4 vh;
            vh[0] = p0[0]; vh[1] = p0[1]; vh[2] = p1[0]; vh[3] = p1[1];
            int lw  = (rl & 15) | (((kw >> 3) & 3) << 4);
            int s   = rl >> 4;
            int off = s * 520 + lw * 8 + (kw & 7);
            *(f16x4*)(Ahi + off) = vh;
        }
        // ---- stage B slabs (g = c)
#pragma unroll
        for (int i = 0; i < 4; ++i) {
            int id = i * 256 + tid;
            int sb = id >> 6;
            int ls = id & 63;
            if (sb < 8) {
                *(f16x8*)(Bhi + sb * 512 + ls * 8) =
                    *(const f16x8*)(wwh + ((sb * 8 + c) * 64 + ls) * 8);
            } else {
                int ct = sb - 8;
                *(f16x8*)(Blo + ct * 512 + ls * 8) =
                    *(const f16x8*)(wwl + ((ct * 8 + c) * 64 + ls) * 8);
            }
        }
        __syncthreads();
        // ---- compute
        f16x8 ah[4], bh[4], bl[4];
#pragma unroll
        for (int rt = 0; rt < 4; ++rt) {
            int s = wr * 4 + rt;
            ah[rt] = *(const f16x8*)(Ahi + s * 520 + l * 8);
        }
#pragma unroll
        for (int ct = 0; ct < 4; ++ct) {
            int s = wc * 4 + ct;
            bh[ct] = *(const f16x8*)(Bhi + s * 512 + l * 8);
            bl[ct] = *(const f16x8*)(Blo + s * 512 + l * 8);
        }
#pragma unroll
        for (int rt = 0; rt < 4; ++rt)
#pragma unroll
            for (int ct = 0; ct < 4; ++ct) {
                acc[rt][ct] = __builtin_amdgcn_mfma_f32_16x16x32_f16(ah[rt], bh[ct], acc[rt][ct], 0, 0, 0);
                acc[rt][ct] = __builtin_amdgcn_mfma_f32_16x16x32_f16(ah[rt], bl[ct], acc[rt][ct], 0, 0, 0);
            }
    }

    // ---- epilogue: +bw, leaky, row L2-norm (128 cols), safediv, store
    const int grp = l >> 4;
#pragma unroll
    for (int rt = 0; rt < 4; ++rt)
#pragma unroll
        for (int ct = 0; ct < 4; ++ct)
#pragma unroll
            for (int r = 0; r < 4; ++r) {
                int col = wc * 64 + ct * 16 + (l & 15);
                float v = acc[rt][ct][r] + bw_s[col];
                acc[rt][ct][r] = (v >= 0.f) ? v : NEG_SLOPE * v;
            }
    float ssq[4][4];
#pragma unroll
    for (int rt = 0; rt < 4; ++rt)
#pragma unroll
        for (int r = 0; r < 4; ++r) {
            float s = 0.f;
#pragma unroll
            for (int ct = 0; ct < 4; ++ct) s += acc[rt][ct][r] * acc[rt][ct][r];
            s += __shfl_xor(s, 1);
            s += __shfl_xor(s, 2);
            s += __shfl_xor(s, 4);
            s += __shfl_xor(s, 8);
            ssq[rt][r] = s;  // sum over this wave's 64 cols
        }
    if ((l & 15) == 0) {
#pragma unroll
        for (int rt = 0; rt < 4; ++rt)
#pragma unroll
            for (int r = 0; r < 4; ++r)
                nbuf[wc][wr * 64 + rt * 16 + grp * 4 + r] = ssq[rt][r];
    }
    __syncthreads();
#pragma unroll
    for (int rt = 0; rt < 4; ++rt)
#pragma unroll
        for (int r = 0; r < 4; ++r) {
            int rowl = wr * 64 + rt * 16 + grp * 4 + r;
            long n = NB + rowl;
            if (n < NNODES) {
                float nrm = sqrtf(nbuf[0][rowl] + nbuf[1][rowl]);
                if (nrm == 0.f) nrm = 1.f;
#pragma unroll
                for (int ct = 0; ct < 4; ++ct) {
                    int col = wc * 64 + ct * 16 + (l & 15);
                    out[n * DOUT + col] = acc[rt][ct][r] / nrm;
                }
            }
        }
}

// ---------------------------------------------------------------- launcher
extern "C" void kernel_launch(void* const* d_in, const int* in_sizes, int n_in,
                              void* d_out, int out_size, void* d_ws, size_t ws_size,
                              hipStream_t stream) {
    const float* h_node  = (const float*)d_in[0];
    const float* h_ngbrs = (const float*)d_in[1];
    const float* alpha   = (const float*)d_in[2];
    const float* Wq      = (const float*)d_in[3];
    const float* bq      = (const float*)d_in[4];
    const float* Ww      = (const float*)d_in[5];
    const float* bw      = (const float*)d_in[6];
    float* out   = (float*)d_out;
    _Float16* ws = (_Float16*)d_ws;

    convert_weights<<<24, 256, 0, stream>>>(Wq, Ww, ws);
    gemm1_agg<<<GG, 512, 0, stream>>>(h_ngbrs, alpha, bq, ws, out);
    // ceil(50000/128) = 391 node tiles
    gemm2_norm<<<391, 256, 0, stream>>>(h_node, bw, ws, out);
}

// Round 11
// 232.766 us; speedup vs baseline: 1.4394x; 1.4394x over previous
//
#include <hip/hip_runtime.h>

#define NNODES 50000
#define DIN 128
#define DHID 128
#define DOUT 128
#define NEG_SLOPE 0.01f
#define NT 12500   // 1,600,000 rows / 128
#define GG 256     // persistent grid: 1 block per CU

typedef _Float16 f16x8 __attribute__((ext_vector_type(8)));
typedef _Float16 f16x4 __attribute__((ext_vector_type(4)));
typedef _Float16 f16x2 __attribute__((ext_vector_type(2)));
typedef float f32x4 __attribute__((ext_vector_type(4)));

__device__ __forceinline__ f16x2 pkrtz(float a, float b) {
    return __builtin_bit_cast(f16x2, __builtin_amdgcn_cvt_pkrtz(a, b));
}

// d_ws layout (halves):
//  WqB hi: [ct(8)][g(4)][l(64)][8]   = 16384 halves
//  WqB lo: 16384
//  WwB hi: [ct(8)][g(8)][l(64)][8]   = 32768 halves
//  WwB lo: 32768
#define WS_WQ_HI 0
#define WS_WQ_LO 16384
#define WS_WW_HI 32768
#define WS_WW_LO 65536

__device__ __forceinline__ void gload_lds16(const float* g, float* lds) {
    __builtin_amdgcn_global_load_lds(
        (const __attribute__((address_space(1))) void*)g,
        (__attribute__((address_space(3))) void*)lds, 16, 0, 0);
}

// ---------------------------------------------------------------- kernel 0
// Convert weights to fp16 hi/lo fragment slabs.
// Fragment convention (mfma_f32_16x16x32_f16):
//   A: row = l&15, k = (l>>4)*8 + j
//   B: col = l&15, k = (l>>4)*8 + j
//   D: col = l&15, row = (l>>4)*4 + r
__global__ void convert_weights(const float* __restrict__ Wq,
                                const float* __restrict__ Ww,
                                _Float16* __restrict__ ws) {
    int id = blockIdx.x * 256 + threadIdx.x;
    if (id < 2048) {  // Wq slots: B[k][col] = Wq[col][k]
        int s  = id;
        int l  = s & 63;
        int g  = (s >> 6) & 3;
        int ct = s >> 8;
        int col = ct * 16 + (l & 15);
        int k0  = g * 32 + (l >> 4) * 8;
        const float* src = Wq + col * DIN + k0;
        f16x8 vh, vl;
#pragma unroll
        for (int j = 0; j < 8; ++j) {
            float v = src[j];
            _Float16 h = (_Float16)v;
            vh[j] = h;
            vl[j] = (_Float16)(v - (float)h);
        }
        *(f16x8*)(ws + WS_WQ_HI + s * 8) = vh;
        *(f16x8*)(ws + WS_WQ_LO + s * 8) = vl;
    } else if (id < 2048 + 4096) {  // Ww slots: B2[k][o] = Ww[o][k]
        int s  = id - 2048;
        int l  = s & 63;
        int g  = (s >> 6) & 7;
        int ct = s >> 9;
        int col = ct * 16 + (l & 15);
        int k0  = g * 32 + (l >> 4) * 8;
        const float* src = Ww + col * (DIN + DHID) + k0;
        f16x8 vh, vl;
#pragma unroll
        for (int j = 0; j < 8; ++j) {
            float v = src[j];
            _Float16 h = (_Float16)v;
            vh[j] = h;
            vl[j] = (_Float16)(v - (float)h);
        }
        *(f16x8*)(ws + WS_WW_HI + s * 8) = vh;
        *(f16x8*)(ws + WS_WW_LO + s * 8) = vl;
    }
}

// ---------------------------------------------------------------- kernel 1
// GEMM1 + leaky + alpha-weighted mean -> hagg (= d_out).
// R9 base (proven 228.6us) with FULL-TILE double-buffer staging:
//  - staging unit = whole 128-row x K=128 tile = 64KB, CONTIGUOUS in hng
//    (R9's k-chunks read 128B @ 512B stride; this is byte-sequential)
//  - 2 x 64KB LDS buffers (128KB static, proven on gfx950 per m201)
//  - ONE vmcnt wait + ONE barrier per tile (R9 had 4; R10's regression
//    showed per-chunk barriers/epilogues cost ~100us)
//  - per-wave queue/tile = S(8) W(2) A(4); wait vmcnt(6) retires exactly
//    the oldest 8 = S(t); stage-to-use distance = 1 tile >> HBM latency
//  - LDS swizzle (both-sides involution): LDS[row][o] holds
//    A[row][o ^ ((row&7)<<4)] via pre-swizzled global source; COMPUTE
//    XORs back -> 2 lanes/bank (free)
//  - prologue ends with vmcnt(0) drain + barrier (R7 lesson)
// Compute per tile/wave: 32 ds_read_b128, 64 pkrtz, 64 MFMA — identical
// math to R9 (single-f16 A, B hi+lo, 2-term).
__global__ __launch_bounds__(512, 2) void gemm1_agg(
    const float* __restrict__ hng,    // [NNODES*32][128]
    const float* __restrict__ alpha,  // [NNODES*32]
    const float* __restrict__ bq,     // [128]
    const _Float16* __restrict__ ws,
    float* __restrict__ hagg)         // [NNODES][128]
{
    __shared__ float As[2][16384];  // 2 x 64KB tile buffers

    const int tid = threadIdx.x;
    const int l   = tid & 63;
    const int wid = tid >> 6;          // 0..7
    const int wr  = wid >> 2;          // 0..1  (row group: 64 rows)
    const int wc  = wid & 3;           // 0..3  (col group: 32 cols)
    const int r16 = l & 15;
    const int kg  = l >> 4;

    const _Float16* wqh = ws + WS_WQ_HI;
    const _Float16* wql = ws + WS_WQ_LO;

    // ---- permanent B fragments: 4 k-frags x 2 col-tiles, hi+lo (64 VGPR)
    f16x8 bh[4][2], bl[4][2];
#pragma unroll
    for (int kf = 0; kf < 4; ++kf)
#pragma unroll
        for (int ct = 0; ct < 2; ++ct) {
            int off = (((wc * 2 + ct) * 4 + kf) * 64 + l) * 8;
            bh[kf][ct] = *(const f16x8*)(wqh + off);
            bl[kf][ct] = *(const f16x8*)(wql + off);
        }

    // ---- staging source offsets (floats). Instr i covers slab bytes
    // [(wid*8+i)*1024, +1024) = 2 rows of 512B. Lane: row += l>>5,
    // o = (l&31)*16. Source pre-swizzled within the row's 512B window.
    int so[8];
#pragma unroll
    for (int i = 0; i < 8; ++i) {
        int row = (wid * 8 + i) * 2 + (l >> 5);
        int o   = (l & 31) * 16;
        so[i]   = row * 128 + ((o ^ ((row & 7) << 4)) >> 2);
    }

    float bqv[2];
#pragma unroll
    for (int ct = 0; ct < 2; ++ct)
        bqv[ct] = bq[wc * 32 + ct * 16 + r16];

#define STAGE(Rb, s)                                                          \
    do {                                                                      \
        _Pragma("unroll")                                                     \
        for (int i_ = 0; i_ < 8; ++i_) {                                      \
            gload_lds16(hng + (long)(Rb)*DIN + so[i_],                        \
                        &As[s][(wid * 8 + i_) * 256]);                        \
        }                                                                     \
    } while (0)

#define COMPUTE(s)                                                            \
    do {                                                                      \
        _Pragma("unroll")                                                     \
        for (int rt_ = 0; rt_ < 4; ++rt_) {                                   \
            int row_ = wr * 64 + rt_ * 16 + r16;                              \
            int asw_ = (row_ & 7) << 4;                                       \
            const char* sb_ = (const char*)&As[s][0] + row_ * 512;            \
            _Pragma("unroll")                                                 \
            for (int kf_ = 0; kf_ < 4; ++kf_) {                               \
                int kb_ = kf_ * 128 + kg * 32;                                \
                f32x4 v0_ = *(const f32x4*)(sb_ + ((kb_ + 0) ^ asw_));        \
                f32x4 v1_ = *(const f32x4*)(sb_ + ((kb_ + 16) ^ asw_));       \
                f16x2 p0_ = pkrtz(v0_[0], v0_[1]);                            \
                f16x2 p1_ = pkrtz(v0_[2], v0_[3]);                            \
                f16x2 p2_ = pkrtz(v1_[0], v1_[1]);                            \
                f16x2 p3_ = pkrtz(v1_[2], v1_[3]);                            \
                f16x8 ah_;                                                    \
                ah_[0] = p0_[0]; ah_[1] = p0_[1];                             \
                ah_[2] = p1_[0]; ah_[3] = p1_[1];                             \
                ah_[4] = p2_[0]; ah_[5] = p2_[1];                             \
                ah_[6] = p3_[0]; ah_[7] = p3_[1];                             \
                _Pragma("unroll")                                             \
                for (int ct_ = 0; ct_ < 2; ++ct_) {                           \
                    acc[rt_][ct_] = __builtin_amdgcn_mfma_f32_16x16x32_f16(   \
                        ah_, bh[kf_][ct_], acc[rt_][ct_], 0, 0, 0);           \
                    acc[rt_][ct_] = __builtin_amdgcn_mfma_f32_16x16x32_f16(   \
                        ah_, bl[kf_][ct_], acc[rt_][ct_], 0, 0, 0);           \
                }                                                             \
            }                                                                 \
        }                                                                     \
    } while (0)

    long t  = blockIdx.x;
    long R0 = t * 128;

    // ---- prologue (order-robust: fully drained below)
    STAGE(R0, 0);
    f32x4 av4[4];
#pragma unroll
    for (int rt = 0; rt < 4; ++rt)
        av4[rt] = *(const f32x4*)(alpha + R0 + wr * 64 + rt * 16 + kg * 4);
    asm volatile("s_waitcnt vmcnt(0)" ::: "memory");
    __builtin_amdgcn_s_barrier();
    __builtin_amdgcn_sched_barrier(0);

    int cur = 0;
    for (;;) {
        const bool last = (t + GG >= NT);
        const long tn   = last ? t : t + GG;   // clamped prefetch target
        const long Rn   = tn * 128;

        f32x4 acc[4][2];
#pragma unroll
        for (int i = 0; i < 4; ++i)
#pragma unroll
            for (int j = 0; j < 2; ++j) acc[i][j] = (f32x4){0.f, 0.f, 0.f, 0.f};

        // ---- wait for S(t): outstanding = S(t)[8], W[2], A[4] = 14;
        //      S(t) are the oldest 8 -> vmcnt(6) retires exactly them.
        asm volatile("s_waitcnt vmcnt(6)" ::: "memory");
        __builtin_amdgcn_s_barrier();
        __builtin_amdgcn_sched_barrier(0);
        // ---- stage next tile into the other buffer (in flight across
        //      the whole compute+epilogue of this tile)
        STAGE(Rn, cur ^ 1);
        __builtin_amdgcn_sched_barrier(0);
        COMPUTE(cur);
        __builtin_amdgcn_sched_barrier(0);

        // ---- epilogue tile t: +bq, leaky, *alpha, reduce 32 rows/node
        {
            float part[2][2] = {{0.f, 0.f}, {0.f, 0.f}};
            float apart[2] = {0.f, 0.f};
#pragma unroll
            for (int rt = 0; rt < 4; ++rt) {
                const int nl = rt >> 1;
#pragma unroll
                for (int r = 0; r < 4; ++r) {
                    float aw = av4[rt][r];
                    apart[nl] += aw;
#pragma unroll
                    for (int ct = 0; ct < 2; ++ct) {
                        float v = acc[rt][ct][r] + bqv[ct];
                        v = (v >= 0.f) ? v : NEG_SLOPE * v;
                        part[nl][ct] += aw * v;
                    }
                }
            }
#pragma unroll
            for (int nl = 0; nl < 2; ++nl) {
                apart[nl] += __shfl_xor(apart[nl], 16);
                apart[nl] += __shfl_xor(apart[nl], 32);
#pragma unroll
                for (int ct = 0; ct < 2; ++ct) {
                    part[nl][ct] += __shfl_xor(part[nl][ct], 16);
                    part[nl][ct] += __shfl_xor(part[nl][ct], 32);
                }
            }
            if (kg < 2) {  // lanes 0..31 -> the W(2) queue slot
                int nl = kg;
                long node = t * 4 + wr * 2 + nl;
                float den = apart[nl];
                if (den == 0.f) den = 1.f;
#pragma unroll
                for (int ct = 0; ct < 2; ++ct) {
                    int col = wc * 32 + ct * 16 + r16;
                    hagg[node * DHID + col] = part[nl][ct] / den;
                }
            }
        }
        __builtin_amdgcn_sched_barrier(0);
        // ---- prefetch alpha for tn (the A(4) queue slot)
#pragma unroll
        for (int rt = 0; rt < 4; ++rt)
            av4[rt] = *(const f32x4*)(alpha + Rn + wr * 64 + rt * 16 + kg * 4);
        __builtin_amdgcn_sched_barrier(0);

        if (last) break;
        t   = tn;
        R0  = Rn;
        cur ^= 1;
    }
    asm volatile("s_waitcnt vmcnt(0)" ::: "memory");  // drain before endpgm

#undef STAGE
#undef COMPUTE
}

// ---------------------------------------------------------------- kernel 2
// GEMM2: out = normalize(leaky(concat(h_node, hagg) @ Ww^T + bw))
// Tile: 128 nodes x 128 out, K=256 in 8 chunks of 32. hagg lives in `out`.
// A single-f16 via pkrtz; B hi+lo; 2 MFMA terms. (unchanged from R9)
__global__ __launch_bounds__(256, 2) void gemm2_norm(
    const float* __restrict__ hnode,  // [NNODES][128]
    const float* __restrict__ bw,     // [128]
    const _Float16* __restrict__ ws,
    float* __restrict__ out)          // [NNODES][128], holds hagg on entry
{
    __shared__ _Float16 Ahi[8 * 520];
    __shared__ _Float16 Bhi[8 * 512];
    __shared__ _Float16 Blo[8 * 512];
    __shared__ float bw_s[128];
    __shared__ float nbuf[2][128];

    const int tid = threadIdx.x;
    const int l   = tid & 63;
    const int wid = tid >> 6;
    const int wr  = wid >> 1, wc = wid & 1;
    const long NB = (long)blockIdx.x * 128;

    if (tid < 128) bw_s[tid] = bw[tid];

    f32x4 acc[4][4];
#pragma unroll
    for (int i = 0; i < 4; ++i)
#pragma unroll
        for (int j = 0; j < 4; ++j) acc[i][j] = (f32x4){0.f, 0.f, 0.f, 0.f};

    const _Float16* wwh = ws + WS_WW_HI;
    const _Float16* wwl = ws + WS_WW_LO;

    for (int c = 0; c < 8; ++c) {
        __syncthreads();
        // ---- stage A: 128 nodes x 32 k of concat(h_node, hagg), f16 single
#pragma unroll
        for (int p = 0; p < 4; ++p) {
            int rl = p * 32 + (tid >> 3);
            long n = NB + rl;
            if (n > NNODES - 1) n = NNODES - 1;  // tail clamp (stores guarded)
            int kw = (tid & 7) * 4;       // within-chunk k
            int kgl = c * 32 + kw;        // global k in 0..255
            const float* g = (kgl < 128) ? (hnode + n * DIN + kgl)
                                         : (out + n * DHID + (kgl - 128));
            f32x4 v = *(const f32x4*)g;
            f16x2 p0 = pkrtz(v[0], v[1]);
            f16x2 p1 = pkrtz(v[2], v[3]);
            f16x4 vh;
            vh[0] = p0[0]; vh[1] = p0[1]; vh[2] = p1[0]; vh[3] = p1[1];
            int lw  = (rl & 15) | (((kw >> 3) & 3) << 4);
            int s   = rl >> 4;
            int off = s * 520 + lw * 8 + (kw & 7);
            *(f16x4*)(Ahi + off) = vh;
        }
        // ---- stage B slabs (g = c)
#pragma unroll
        for (int i = 0; i < 4; ++i) {
            int id = i * 256 + tid;
            int sb = id >> 6;
            int ls = id & 63;
            if (sb < 8) {
                *(f16x8*)(Bhi + sb * 512 + ls * 8) =
                    *(const f16x8*)(wwh + ((sb * 8 + c) * 64 + ls) * 8);
            } else {
                int ct = sb - 8;
                *(f16x8*)(Blo + ct * 512 + ls * 8) =
                    *(const f16x8*)(wwl + ((ct * 8 + c) * 64 + ls) * 8);
            }
        }
        __syncthreads();
        // ---- compute
        f16x8 ah[4], bh[4], bl[4];
#pragma unroll
        for (int rt = 0; rt < 4; ++rt) {
            int s = wr * 4 + rt;
            ah[rt] = *(const f16x8*)(Ahi + s * 520 + l * 8);
        }
#pragma unroll
        for (int ct = 0; ct < 4; ++ct) {
            int s = wc * 4 + ct;
            bh[ct] = *(const f16x8*)(Bhi + s * 512 + l * 8);
            bl[ct] = *(const f16x8*)(Blo + s * 512 + l * 8);
        }
#pragma unroll
        for (int rt = 0; rt < 4; ++rt)
#pragma unroll
            for (int ct = 0; ct < 4; ++ct) {
                acc[rt][ct] = __builtin_amdgcn_mfma_f32_16x16x32_f16(ah[rt], bh[ct], acc[rt][ct], 0, 0, 0);
                acc[rt][ct] = __builtin_amdgcn_mfma_f32_16x16x32_f16(ah[rt], bl[ct], acc[rt][ct], 0, 0, 0);
            }
    }

    // ---- epilogue: +bw, leaky, row L2-norm (128 cols), safediv, store
    const int grp = l >> 4;
#pragma unroll
    for (int rt = 0; rt < 4; ++rt)
#pragma unroll
        for (int ct = 0; ct < 4; ++ct)
#pragma unroll
            for (int r = 0; r < 4; ++r) {
                int col = wc * 64 + ct * 16 + (l & 15);
                float v = acc[rt][ct][r] + bw_s[col];
                acc[rt][ct][r] = (v >= 0.f) ? v : NEG_SLOPE * v;
            }
    float ssq[4][4];
#pragma unroll
    for (int rt = 0; rt < 4; ++rt)
#pragma unroll
        for (int r = 0; r < 4; ++r) {
            float s = 0.f;
#pragma unroll
            for (int ct = 0; ct < 4; ++ct) s += acc[rt][ct][r] * acc[rt][ct][r];
            s += __shfl_xor(s, 1);
            s += __shfl_xor(s, 2);
            s += __shfl_xor(s, 4);
            s += __shfl_xor(s, 8);
            ssq[rt][r] = s;  // sum over this wave's 64 cols
        }
    if ((l & 15) == 0) {
#pragma unroll
        for (int rt = 0; rt < 4; ++rt)
#pragma unroll
            for (int r = 0; r < 4; ++r)
                nbuf[wc][wr * 64 + rt * 16 + grp * 4 + r] = ssq[rt][r];
    }
    __syncthreads();
#pragma unroll
    for (int rt = 0; rt < 4; ++rt)
#pragma unroll
        for (int r = 0; r < 4; ++r) {
            int rowl = wr * 64 + rt * 16 + grp * 4 + r;
            long n = NB + rowl;
            if (n < NNODES) {
                float nrm = sqrtf(nbuf[0][rowl] + nbuf[1][rowl]);
                if (nrm == 0.f) nrm = 1.f;
#pragma unroll
                for (int ct = 0; ct < 4; ++ct) {
                    int col = wc * 64 + ct * 16 + (l & 15);
                    out[n * DOUT + col] = acc[rt][ct][r] / nrm;
                }
            }
        }
}

// ---------------------------------------------------------------- launcher
extern "C" void kernel_launch(void* const* d_in, const int* in_sizes, int n_in,
                              void* d_out, int out_size, void* d_ws, size_t ws_size,
                              hipStream_t stream) {
    const float* h_node  = (const float*)d_in[0];
    const float* h_ngbrs = (const float*)d_in[1];
    const float* alpha   = (const float*)d_in[2];
    const float* Wq      = (const float*)d_in[3];
    const float* bq      = (const float*)d_in[4];
    const float* Ww      = (const float*)d_in[5];
    const float* bw      = (const float*)d_in[6];
    float* out   = (float*)d_out;
    _Float16* ws = (_Float16*)d_ws;

    convert_weights<<<24, 256, 0, stream>>>(Wq, Ww, ws);
    gemm1_agg<<<GG, 512, 0, stream>>>(h_ngbrs, alpha, bq, ws, out);
    // ceil(50000/128) = 391 node tiles
    gemm2_norm<<<391, 256, 0, stream>>>(h_node, bw, ws, out);
}